// Round 27
// baseline (224.162 us; speedup 1.0000x reference)
//
#include <hip/hip_runtime.h>

#define TS 40
#define BT 64        // batch per block = 4 teams x 16
#define NT 512       // 8 waves: team tm = w>>1, half ws = w&1 (A: mt 0..12, B: mt 13..24)
#define NMT 25       // m-tiles of 16 rows ; M = 400 = 100 units x 4 gates

typedef short bf16x8 __attribute__((ext_vector_type(8)));
typedef float f32x4 __attribute__((ext_vector_type(4)));
typedef float f32x2 __attribute__((ext_vector_type(2)));

// LDS (129024 B, 1 block/CU, 8 waves = 2/SIMD):
//  [0,102400)        As[400][128] bf16, 16B-chunk XOR-swizzled by (row&15) [R26 fix]
//  [102400,128000)   hx: h-exchange u16 [2 buf][4 team][25 mt][4 lg][16 lb]
//  [128000,129024)   px: act partials f32 [2 buf][4 team][2 ws][16 lb]
//  init scratch aliases As: W2s@0 (40000) ; h1s@40000 (25600) ; projs@65600 (25600)
#define HX_OFF   102400
#define PX_OFF   128000
#define SMEM_BYTES 129024
#define W2S_OFF  0
#define H1S_OFF  40000
#define PROJ_OFF 65600

__device__ __forceinline__ unsigned short f2bf(float x) {
    unsigned u = __float_as_uint(x);
    unsigned r = u + 0x7fffu + ((u >> 16) & 1u);
    return (unsigned short)(r >> 16);
}
__device__ __forceinline__ float bf2f(unsigned short s) {
    return __uint_as_float(((unsigned)s) << 16);
}
__device__ __forceinline__ float sigf(float x) {
    return __builtin_amdgcn_rcpf(1.0f + __expf(-x));
}
__device__ __forceinline__ float tanhf_(float x) {
    return 2.0f * __builtin_amdgcn_rcpf(1.0f + __expf(-2.0f * x)) - 1.0f;
}

// Row/col permuted weight build (verified R16/R17/R23, absmax 3.9e-3).
__global__ void prep_kernel(const float* __restrict__ Wr, const float* __restrict__ Wk,
                            unsigned short* __restrict__ Am, unsigned short* __restrict__ Ah,
                            unsigned short* __restrict__ Al) {
    int gid = blockIdx.x * 256 + threadIdx.x;   // 400*128 = 51200
    int r = gid >> 7, k = gid & 127;
    int mtr = r >> 4, lgr = (r >> 2) & 3, g = r & 3;
    int col = g * 100 + (4 * mtr + lgr);
    int kc = k >> 5, lgk = (k >> 3) & 3, jj = k & 7;
    float wm = 0.f, wkv = 0.f;
    if (jj <= 6) {
        int mtk = 4 * jj + kc;
        if (mtk <= 24) {
            int su = 4 * mtk + lgk;
            wm  = Wr[su * 400 + col];
            wkv = Wk[su * 400 + col];
        }
    } else {
        int renv = 4 * kc + lgk;
        if (renv <= 8) wm = Wk[(100 + renv) * 400 + col];
    }
    unsigned short hi = f2bf(wkv);
    Am[gid] = f2bf(wm);
    Ah[gid] = hi;
    Al[gid] = f2bf(wkv - bf2f(hi));
}

#define ENV_X9(c0, c1, c2, cs)                                              \
    const float f_veh_v = c0[1], m_veh_v = c0[2];                           \
    const float f_glob_x = c1[0], m_glob_x = c1[1];                         \
    const float ef_dv_t = c1[2], ef_dx_t = c1[3];                           \
    const float em_dv_t = c2[0], em_dx_t = c2[1];                           \
    const float f_ex = c2[2], m_ex = c2[3];                                 \
    const float ef_dx = (f_glob_x - ego_x) * f_ex + (1.f - f_ex) * ef_dx_t; \
    const float em_dx = (m_glob_x - ego_x) * m_ex + (1.f - m_ex) * em_dx_t; \
    const float ef_dv = (ego_v - f_veh_v) * f_ex + (1.f - f_ex) * ef_dv_t;  \
    const float em_dv = (ego_v - m_veh_v) * m_ex + (1.f - m_ex) * em_dv_t;  \
    const float x90 = cs[0], x91 = cs[1];                                   \
    const float x92 = (ego_v   - msr[0]) * isr[0];                          \
    const float x93 = (f_veh_v - msr[1]) * isr[1];                          \
    const float x94 = (m_veh_v - msr[2]) * isr[2];                          \
    const float x95 = (ef_dv   - msr[3]) * isr[3];                          \
    const float x96 = (ef_dx   - msr[4]) * isr[4];                          \
    const float x97 = (em_dv   - msr[5]) * isr[5];                          \
    const float x98 = (em_dx   - msr[6]) * isr[6];

// env slot (kc, jj=7) holds x9[4*kc + lg]
#define PACK_ENV_HI(DH)                                                     \
    {                                                                       \
        const float e0 = (lg==0)?x90:(lg==1)?x91:(lg==2)?x92:x93;           \
        const float e1 = (lg==0)?x94:(lg==1)?x95:(lg==2)?x96:x97;           \
        const float e2 = (lg==0)?x98:0.f;                                   \
        DH[0][7] = (short)f2bf(e0);                                         \
        DH[1][7] = (short)f2bf(e1);                                         \
        DH[2][7] = (short)f2bf(e2);                                         \
        DH[3][7] = 0;                                                       \
    }

// gk init for own mt range (contraction over full K; env slots of bh are zero here)
#define GK_INIT(MT0, CNT)                                                          \
    _Pragma("unroll")                                                              \
    for (int i = 0; i < CNT; ++i) {                                                \
        const int mt = MT0 + i;                                                    \
        f32x4 ac = (f32x4){0.f, 0.f, 0.f, 0.f};                                    \
        _Pragma("unroll")                                                          \
        for (int kc = 0; kc < 4; ++kc) {                                           \
            const int row = 16 * mt + lb;                                          \
            bf16x8 ah = *(const bf16x8*)(Ah + row * 128 + kc * 32 + lg * 8);       \
            bf16x8 al = *(const bf16x8*)(Al + row * 128 + kc * 32 + lg * 8);       \
            ac = __builtin_amdgcn_mfma_f32_16x16x32_bf16(ah, bh[kc],  ac, 0,0,0);  \
            ac = __builtin_amdgcn_mfma_f32_16x16x32_bf16(ah, bl_[kc], ac, 0,0,0);  \
            ac = __builtin_amdgcn_mfma_f32_16x16x32_bf16(al, bh[kc],  ac, 0,0,0);  \
        }                                                                          \
        const int u = 4 * mt + lg;                                                 \
        const float q0 = ac[0] + bl[u];                                            \
        const float q1 = ac[1] + bl[100 + u];                                      \
        const float q2 = ac[2] + bl[200 + u];                                      \
        const float q3 = ac[3] + bl[300 + u];                                      \
        asm volatile("v_accvgpr_write_b32 %0, %1" : "=a"(gka[4*i+0]) : "v"(q0));   \
        asm volatile("v_accvgpr_write_b32 %0, %1" : "=a"(gka[4*i+1]) : "v"(q1));   \
        asm volatile("v_accvgpr_write_b32 %0, %1" : "=a"(gka[4*i+2]) : "v"(q2));   \
        asm volatile("v_accvgpr_write_b32 %0, %1" : "=a"(gka[4*i+3]) : "v"(q3));   \
    }

// per-step body over own mt range: MFMA z, gates, h -> nbh(own slot) + hx LDS
#define MT_BODY(MT0, CNT)                                                          \
    _Pragma("unroll")                                                              \
    for (int i = 0; i < CNT; ++i) {                                                \
        const int mt = MT0 + i;                                                    \
        float g0, g1, g2, g3;                                                      \
        asm("v_accvgpr_read_b32 %0, %1" : "=v"(g0) : "a"(gka[4*i+0]));             \
        asm("v_accvgpr_read_b32 %0, %1" : "=v"(g1) : "a"(gka[4*i+1]));             \
        asm("v_accvgpr_read_b32 %0, %1" : "=v"(g2) : "a"(gka[4*i+2]));             \
        asm("v_accvgpr_read_b32 %0, %1" : "=v"(g3) : "a"(gka[4*i+3]));             \
        f32x4 ac = (f32x4){g0, g1, g2, g3};                                        \
        const char* ap = Abase + mt * 4096;                                        \
        bf16x8 a0 = *(const bf16x8*)(ap + k0);                                     \
        ac = __builtin_amdgcn_mfma_f32_16x16x32_bf16(a0, bh[0], ac, 0, 0, 0);      \
        bf16x8 a1 = *(const bf16x8*)(ap + k1);                                     \
        ac = __builtin_amdgcn_mfma_f32_16x16x32_bf16(a1, bh[1], ac, 0, 0, 0);      \
        bf16x8 a2 = *(const bf16x8*)(ap + k2);                                     \
        ac = __builtin_amdgcn_mfma_f32_16x16x32_bf16(a2, bh[2], ac, 0, 0, 0);      \
        bf16x8 a3 = *(const bf16x8*)(ap + k3);                                     \
        ac = __builtin_amdgcn_mfma_f32_16x16x32_bf16(a3, bh[3], ac, 0, 0, 0);      \
        const float cc = sigf(ac[1]) * c_st[i] + sigf(ac[0]) * tanhf_(ac[2]);      \
        const float hh = sigf(ac[3]) * tanhf_(cc);                                 \
        c_st[i] = cc;                                                              \
        pact += hh * wd_reg[i];                                                    \
        const unsigned short hb = f2bf(hh);                                        \
        nbh[mt & 3][mt >> 2] = (short)hb;                                          \
        *(unsigned short*)(sm + HX_OFF + ((((cb*4)+tm)*25 + mt)*64 + lg*16 + lb)*2) = hb; \
    }

// read the other wave's half from hx into nbh slots
#define OTHER_READ(MT0, CNT)                                                       \
    _Pragma("unroll")                                                              \
    for (int i = 0; i < CNT; ++i) {                                                \
        const int mt = MT0 + i;                                                    \
        nbh[mt & 3][mt >> 2] = *(const short*)(sm + HX_OFF +                       \
            ((((cb*4)+tm)*25 + mt)*64 + lg*16 + lb)*2);                            \
    }

__global__ __launch_bounds__(NT, 2)
void fwdsim_kernel(const float* __restrict__ sampled_z,
                   const float* __restrict__ idm_s,
                   const float* __restrict__ sdv_acts,
                   const float* __restrict__ W1, const float* __restrict__ b1,
                   const float* __restrict__ W2, const float* __restrict__ b2,
                   const float* __restrict__ bl, const float* __restrict__ Wd,
                   const float* __restrict__ bd,
                   const float* __restrict__ sc_mean, const float* __restrict__ sc_var,
                   const unsigned short* __restrict__ Am,
                   const unsigned short* __restrict__ Ah,
                   const unsigned short* __restrict__ Al,
                   float* __restrict__ out) {
    __shared__ char sm[SMEM_BYTES];
    float* W2s  = (float*)(sm + W2S_OFF);
    float* h1s  = (float*)(sm + H1S_OFF);
    float* projs= (float*)(sm + PROJ_OFF);

    const int tid = threadIdx.x;
    const int w = tid >> 6, l = tid & 63, lb = l & 15, lg = l >> 4;
    const int tm = w >> 1, ws = w & 1;          // team, half (A: mt 0..12, B: 13..24)
    const int blk = blockIdx.x;
    const int bloc = tm * 16 + lb;              // batch-in-block (teams share 16 batch)
    const size_t eg = (size_t)(blk * BT + bloc);

    // ---------------- init: stage W2 ; h1 = relu(z@W1+b1) ----------------
    for (int i = tid; i < 2500; i += NT) ((f32x4*)W2s)[i] = ((const f32x4*)W2)[i];
    {
        const int e = tid >> 3, q = tid & 7;    // 64 elems x 8 threads x 13 cols
        const int egi = blk * BT + e;
        float zv[6];
        #pragma unroll
        for (int r = 0; r < 6; ++r) zv[r] = sampled_z[egi * 6 + r];
        #pragma unroll
        for (int m = 0; m < 13; ++m) {
            const int c = q * 13 + m;
            if (c < 100) {
                float a = b1[c];
                #pragma unroll
                for (int r = 0; r < 6; ++r) a += zv[r] * W1[r * 100 + c];
                h1s[e * 100 + c] = fmaxf(a, 0.f);
            }
        }
    }
    __syncthreads();

    // ---------------- proj = relu(h1 @ W2 + b2) ----------------
    {
        const int e = tid >> 3, q = tid & 7;
        for (int m = 0; m < 13; ++m) {
            const int c = q * 13 + m;
            if (c < 100) {
                float a = b2[c];
                for (int k = 0; k < 100; ++k) a += h1s[e * 100 + k] * W2s[k * 100 + c];
                projs[e * 100 + c] = fmaxf(a, 0.f);
            }
        }
    }
    __syncthreads();   // projs ready

    // ---------------- per-lane state (own mt range) ----------------
    float c_st[13], wd_reg[13];
    {
        const int mt0i = ws * 13, nmw = 13 - ws;
        #pragma unroll
        for (int i = 0; i < 13; ++i) { c_st[i] = 0.f; wd_reg[i] = 0.f; }
        #pragma unroll
        for (int i = 0; i < 13; ++i) {
            if (i < nmw) {
                const int u = 4 * (mt0i + i) + lg;
                wd_reg[i] = Wd[u];
                c_st[i]   = projs[bloc * 100 + u];
            }
        }
    }

    // B-frags: proj in sigma layout (h0 = proj); bl_ only for gk init
    bf16x8 bh[4], bl_[4];
    #pragma unroll
    for (int kc = 0; kc < 4; ++kc) {
        bh[kc]  = (bf16x8){0,0,0,0,0,0,0,0};
        bl_[kc] = (bf16x8){0,0,0,0,0,0,0,0};
    }
    #pragma unroll
    for (int mt = 0; mt < NMT; ++mt) {
        const int kcq = mt & 3, jjq = mt >> 2;
        const float v = projs[bloc * 100 + 4 * mt + lg];
        const unsigned short hi = f2bf(v);
        bh[kcq][jjq]  = (short)hi;
        bl_[kcq][jjq] = (short)f2bf(v - bf2f(hi));
    }

    float msr[7], isr[7];
    #pragma unroll
    for (int r = 0; r < 7; ++r) { msr[r] = sc_mean[r]; isr[r] = 1.0f / sqrtf(sc_var[r]); }
    const float bd0 = bd[0];

    // ---------------- gk (own mt range) -> AGPRs, full hi/lo precision ----------------
    float gka[52];
    if (ws == 0) { GK_INIT(0, 13) } else { GK_INIT(13, 12) }
    __syncthreads();   // all projs reads done -> scratch dead

    // ---------------- stage As (full-nibble swizzle) ; env t=0 ----------------
    #pragma unroll
    for (int i = 0; i < 13; ++i) {
        const int ch = tid + i * NT;            // 6400 chunks of 16B
        if (ch < 6400) {
            const int row = ch >> 4, c16 = ch & 15;
            *(bf16x8*)(sm + row * 256 + ((c16 * 16) ^ ((row & 15) << 4))) =
                *(const bf16x8*)(Am + row * 128 + c16 * 8);
        }
    }
    float ego_v, ego_x;
    f32x4 cur0, cur1, cur2;
    f32x2 curs;
    {
        const float* ip = idm_s + (eg * TS) * 12;
        f32x4 i0 = *(const f32x4*)ip, i1 = *(const f32x4*)(ip + 4), i2 = *(const f32x4*)(ip + 8);
        f32x2 s0 = *(const f32x2*)(sdv_acts + (eg * TS) * 2);
        ego_v = i0[0]; ego_x = i0[3];
        ENV_X9(i0, i1, i2, s0)
        PACK_ENV_HI(bh)
        const float* ip1 = idm_s + (eg * TS + 1) * 12;
        cur0 = *(const f32x4*)ip1; cur1 = *(const f32x4*)(ip1 + 4); cur2 = *(const f32x4*)(ip1 + 8);
        curs = *(const f32x2*)(sdv_acts + (eg * TS + 1) * 2);
    }
    __syncthreads();   // As ready

    // ---------------- 40-step recurrence: M-split team, 1 barrier/step ----------------
    // read swizzle: lane lb reads row 16*mt+lb -> row&15 == lb
    const int sw = lb << 4;
    const int k0 = (16 * lg) ^ sw;
    const int k1 = (64 + 16 * lg) ^ sw;
    const int k2 = (128 + 16 * lg) ^ sw;
    const int k3 = (192 + 16 * lg) ^ sw;
    const char* Abase = sm + lb * 256;

    int cb = 0;
    for (int t = 0; t < TS; ++t) {
        bf16x8 nbh[4];
        float pact = 0.f;
        if (ws == 0) { MT_BODY(0, 13) } else { MT_BODY(13, 12) }
        pact += __shfl_xor(pact, 16);
        pact += __shfl_xor(pact, 32);
        if (l < 16)
            *(float*)(sm + PX_OFF + ((((cb*4)+tm)*2 + ws)*16 + l) * 4) = pact;
        __syncthreads();   // hx + px visible

        const float p0 = *(const float*)(sm + PX_OFF + ((((cb*4)+tm)*2 + 0)*16 + lb) * 4);
        const float p1 = *(const float*)(sm + PX_OFF + ((((cb*4)+tm)*2 + 1)*16 + lb) * 4);
        const float act = p0 + p1 + bd0;
        if (ws == 0 && lg == 0) out[eg * TS + t] = act;

        if (t < TS - 1) {
            ego_v += act * 0.1f;
            ego_x += ego_v * 0.1f + 0.005f * act;
            ENV_X9(cur0, cur1, cur2, curs)
            if (ws == 0) { OTHER_READ(13, 12) } else { OTHER_READ(0, 13) }
            PACK_ENV_HI(nbh)
            nbh[1][6] = 0; nbh[2][6] = 0; nbh[3][6] = 0;   // mt 25..27 stay zero
            #pragma unroll
            for (int kc = 0; kc < 4; ++kc) bh[kc] = nbh[kc];
            if (t < TS - 2) {
                const float* ip = idm_s + (eg * TS + t + 2) * 12;
                cur0 = *(const f32x4*)ip; cur1 = *(const f32x4*)(ip + 4); cur2 = *(const f32x4*)(ip + 8);
                curs = *(const f32x2*)(sdv_acts + (eg * TS + t + 2) * 2);
            }
        }
        cb ^= 1;
    }
}

extern "C" void kernel_launch(void* const* d_in, const int* in_sizes, int n_in,
                              void* d_out, int out_size, void* d_ws, size_t ws_size,
                              hipStream_t stream) {
    const float* sampled_z = (const float*)d_in[0];
    const float* idm_s     = (const float*)d_in[1];
    const float* sdv_acts  = (const float*)d_in[2];
    const float* W1        = (const float*)d_in[3];
    const float* b1        = (const float*)d_in[4];
    const float* W2        = (const float*)d_in[5];
    const float* b2        = (const float*)d_in[6];
    const float* Wk        = (const float*)d_in[7];
    const float* Wr        = (const float*)d_in[8];
    const float* bl        = (const float*)d_in[9];
    const float* Wd        = (const float*)d_in[10];
    const float* bd        = (const float*)d_in[11];
    const float* sc_mean   = (const float*)d_in[12];
    const float* sc_var    = (const float*)d_in[13];
    float* out = (float*)d_out;

    unsigned short* Am = (unsigned short*)d_ws;       // [400][128] bf16 sigma-layout
    unsigned short* Ah = Am + 400 * 128;              // Wk hi
    unsigned short* Al = Ah + 400 * 128;              // Wk lo

    hipLaunchKernelGGL(prep_kernel, dim3(200), dim3(256), 0, stream, Wr, Wk, Am, Ah, Al);
    hipLaunchKernelGGL(fwdsim_kernel, dim3(16384 / BT), dim3(NT), 0, stream,
                       sampled_z, idm_s, sdv_acts, W1, b1, W2, b2, bl, Wd, bd,
                       sc_mean, sc_var, Am, Ah, Al, out);
}

// Round 28
// 207.746 us; speedup vs baseline: 1.0790x; 1.0790x over previous
//
#include <hip/hip_runtime.h>

#define TS 40
#define BT 64        // batch per block = 4 waves x 16
#define NT 256
#define NMT 25       // m-tiles of 16 rows ; M = 400 = 100 units x 4 gates

typedef short bf16x8 __attribute__((ext_vector_type(8)));
typedef float f32x4 __attribute__((ext_vector_type(4)));
typedef float f32x2 __attribute__((ext_vector_type(2)));

// LDS (102400 B): As[400][128] bf16, 16B-chunk XOR-swizzled by (row&15)
// (full nibble: lanes lb and lb+8 previously aliased with &7 -> 4 cyc/read conflicts).
// Init scratch aliases it: W2s@0 (40000) ; h1s@40000 (25600) ; projs@65600 (25600)
#define W2S_OFF  0
#define H1S_OFF  40000
#define PROJ_OFF 65600
#define SMEM_BYTES 102400

__device__ __forceinline__ unsigned short f2bf(float x) {
    unsigned u = __float_as_uint(x);
    unsigned r = u + 0x7fffu + ((u >> 16) & 1u);
    return (unsigned short)(r >> 16);
}
__device__ __forceinline__ float bf2f(unsigned short s) {
    return __uint_as_float(((unsigned)s) << 16);
}
__device__ __forceinline__ float sigf(float x) {
    return __builtin_amdgcn_rcpf(1.0f + __expf(-x));
}
__device__ __forceinline__ float tanhf_(float x) {
    return 2.0f * __builtin_amdgcn_rcpf(1.0f + __expf(-2.0f * x)) - 1.0f;
}

// Row/col permuted weight build (verified R16/R17/R23, absmax 3.9e-3).
__global__ void prep_kernel(const float* __restrict__ Wr, const float* __restrict__ Wk,
                            unsigned short* __restrict__ Am, unsigned short* __restrict__ Ah,
                            unsigned short* __restrict__ Al) {
    int gid = blockIdx.x * 256 + threadIdx.x;   // 400*128 = 51200
    int r = gid >> 7, k = gid & 127;
    int mtr = r >> 4, lgr = (r >> 2) & 3, g = r & 3;
    int col = g * 100 + (4 * mtr + lgr);
    int kc = k >> 5, lgk = (k >> 3) & 3, jj = k & 7;
    float wm = 0.f, wkv = 0.f;
    if (jj <= 6) {
        int mtk = 4 * jj + kc;
        if (mtk <= 24) {
            int su = 4 * mtk + lgk;
            wm  = Wr[su * 400 + col];
            wkv = Wk[su * 400 + col];
        }
    } else {
        int renv = 4 * kc + lgk;
        if (renv <= 8) wm = Wk[(100 + renv) * 400 + col];
    }
    unsigned short hi = f2bf(wkv);
    Am[gid] = f2bf(wm);
    Ah[gid] = hi;
    Al[gid] = f2bf(wkv - bf2f(hi));
}

#define ENV_X9(c0, c1, c2, cs)                                              \
    const float f_veh_v = c0[1], m_veh_v = c0[2];                           \
    const float f_glob_x = c1[0], m_glob_x = c1[1];                         \
    const float ef_dv_t = c1[2], ef_dx_t = c1[3];                           \
    const float em_dv_t = c2[0], em_dx_t = c2[1];                           \
    const float f_ex = c2[2], m_ex = c2[3];                                 \
    const float ef_dx = (f_glob_x - ego_x) * f_ex + (1.f - f_ex) * ef_dx_t; \
    const float em_dx = (m_glob_x - ego_x) * m_ex + (1.f - m_ex) * em_dx_t; \
    const float ef_dv = (ego_v - f_veh_v) * f_ex + (1.f - f_ex) * ef_dv_t;  \
    const float em_dv = (ego_v - m_veh_v) * m_ex + (1.f - m_ex) * em_dv_t;  \
    const float x90 = cs[0], x91 = cs[1];                                   \
    const float x92 = (ego_v   - msr[0]) * isr[0];                          \
    const float x93 = (f_veh_v - msr[1]) * isr[1];                          \
    const float x94 = (m_veh_v - msr[2]) * isr[2];                          \
    const float x95 = (ef_dv   - msr[3]) * isr[3];                          \
    const float x96 = (ef_dx   - msr[4]) * isr[4];                          \
    const float x97 = (em_dv   - msr[5]) * isr[5];                          \
    const float x98 = (em_dx   - msr[6]) * isr[6];

// env slot (kc, jj=7) holds x9[4*kc + lg] -- hi only (loop runs single-stream)
#define PACK_ENV_HI(DH)                                                     \
    {                                                                       \
        const float e0 = (lg==0)?x90:(lg==1)?x91:(lg==2)?x92:x93;           \
        const float e1 = (lg==0)?x94:(lg==1)?x95:(lg==2)?x96:x97;           \
        const float e2 = (lg==0)?x98:0.f;                                   \
        DH[0][7] = (short)f2bf(e0);                                         \
        DH[1][7] = (short)f2bf(e1);                                         \
        DH[2][7] = (short)f2bf(e2);                                         \
        DH[3][7] = 0;                                                       \
    }

__global__ __launch_bounds__(NT, 1)
void fwdsim_kernel(const float* __restrict__ sampled_z,
                   const float* __restrict__ idm_s,
                   const float* __restrict__ sdv_acts,
                   const float* __restrict__ W1, const float* __restrict__ b1,
                   const float* __restrict__ W2, const float* __restrict__ b2,
                   const float* __restrict__ bl, const float* __restrict__ Wd,
                   const float* __restrict__ bd,
                   const float* __restrict__ sc_mean, const float* __restrict__ sc_var,
                   const unsigned short* __restrict__ Am,
                   const unsigned short* __restrict__ Ah,
                   const unsigned short* __restrict__ Al,
                   float* __restrict__ out) {
    __shared__ char sm[SMEM_BYTES];
    float* W2s  = (float*)(sm + W2S_OFF);
    float* h1s  = (float*)(sm + H1S_OFF);
    float* projs= (float*)(sm + PROJ_OFF);

    const int tid = threadIdx.x;
    const int w = tid >> 6, l = tid & 63, lb = l & 15, lg = l >> 4;
    const int blk = blockIdx.x;
    const int bloc = w * 16 + lb;               // 0..63 batch-in-block
    const size_t eg = (size_t)(blk * BT + bloc);

    // ---------------- init: stage W2 ; h1 = relu(z@W1+b1) ----------------
    for (int i = tid; i < 2500; i += NT) ((f32x4*)W2s)[i] = ((const f32x4*)W2)[i];
    {
        const int e = tid >> 2, q = tid & 3;    // 64 elems x 4 threads x 25 cols
        const int egi = blk * BT + e;
        float zv[6];
        #pragma unroll
        for (int r = 0; r < 6; ++r) zv[r] = sampled_z[egi * 6 + r];
        for (int m = 0; m < 25; ++m) {
            const int c = q * 25 + m;
            float a = b1[c];
            #pragma unroll
            for (int r = 0; r < 6; ++r) a += zv[r] * W1[r * 100 + c];
            h1s[e * 100 + c] = fmaxf(a, 0.f);
        }
    }
    __syncthreads();

    // ---------------- proj = relu(h1 @ W2 + b2) ----------------
    {
        const int e = tid >> 2, q = tid & 3;
        for (int m = 0; m < 25; ++m) {
            const int c = q * 25 + m;
            float a = b2[c];
            for (int k = 0; k < 100; ++k) a += h1s[e * 100 + k] * W2s[k * 100 + c];
            projs[e * 100 + c] = fmaxf(a, 0.f);
        }
    }
    __syncthreads();   // projs ready

    // ---------------- per-lane state ----------------
    float c_st[NMT], wd_reg[NMT];
    #pragma unroll
    for (int mt = 0; mt < NMT; ++mt) {
        const int u = 4 * mt + lg;              // always < 100
        wd_reg[mt] = Wd[u];
        c_st[mt]   = projs[bloc * 100 + u];
    }

    // B-frags: proj in sigma layout (h0 = proj); bl_ used only for gk init
    bf16x8 bh[4], bl_[4];
    #pragma unroll
    for (int kc = 0; kc < 4; ++kc) {
        bh[kc]  = (bf16x8){0,0,0,0,0,0,0,0};
        bl_[kc] = (bf16x8){0,0,0,0,0,0,0,0};
    }
    #pragma unroll
    for (int mt = 0; mt < NMT; ++mt) {
        const int kcq = mt & 3, jjq = mt >> 2;
        const float v = projs[bloc * 100 + 4 * mt + lg];
        const unsigned short hi = f2bf(v);
        bh[kcq][jjq]  = (short)hi;
        bl_[kcq][jjq] = (short)f2bf(v - bf2f(hi));
    }

    float msr[7], isr[7];
    #pragma unroll
    for (int r = 0; r < 7; ++r) { msr[r] = sc_mean[r]; isr[r] = 1.0f / sqrtf(sc_var[r]); }
    const float bd0 = bd[0];

    // ---------------- gk = bl + Wk_sigma @ proj -> AGPRs (full hi/lo precision) ----------------
    float gka[NMT * 4];
    #pragma unroll
    for (int mt = 0; mt < NMT; ++mt) {
        f32x4 ac = (f32x4){0.f, 0.f, 0.f, 0.f};
        #pragma unroll
        for (int kc = 0; kc < 4; ++kc) {
            const int row = 16 * mt + lb;
            bf16x8 ah = *(const bf16x8*)(Ah + row * 128 + kc * 32 + lg * 8);
            bf16x8 al = *(const bf16x8*)(Al + row * 128 + kc * 32 + lg * 8);
            ac = __builtin_amdgcn_mfma_f32_16x16x32_bf16(ah, bh[kc],  ac, 0, 0, 0);
            ac = __builtin_amdgcn_mfma_f32_16x16x32_bf16(ah, bl_[kc], ac, 0, 0, 0);
            ac = __builtin_amdgcn_mfma_f32_16x16x32_bf16(al, bh[kc],  ac, 0, 0, 0);
        }
        const int u = 4 * mt + lg;
        const float g0 = ac[0] + bl[u];
        const float g1 = ac[1] + bl[100 + u];
        const float g2 = ac[2] + bl[200 + u];
        const float g3 = ac[3] + bl[300 + u];
        asm volatile("v_accvgpr_write_b32 %0, %1" : "=a"(gka[4 * mt + 0]) : "v"(g0));
        asm volatile("v_accvgpr_write_b32 %0, %1" : "=a"(gka[4 * mt + 1]) : "v"(g1));
        asm volatile("v_accvgpr_write_b32 %0, %1" : "=a"(gka[4 * mt + 2]) : "v"(g2));
        asm volatile("v_accvgpr_write_b32 %0, %1" : "=a"(gka[4 * mt + 3]) : "v"(g3));
    }
    __syncthreads();   // all projs reads done -> scratch dead

    // ---------------- stage As (full-nibble swizzle) ; env t=0 in parallel ----------------
    #pragma unroll
    for (int i = 0; i < 25; ++i) {
        const int ch = tid + i * NT;            // 6400 chunks of 16B
        const int row = ch >> 4, c16 = ch & 15;
        *(bf16x8*)(sm + row * 256 + ((c16 * 16) ^ ((row & 15) << 4))) =
            *(const bf16x8*)(Am + row * 128 + c16 * 8);
    }
    float ego_v, ego_x;
    f32x4 cur0, cur1, cur2;
    f32x2 curs;
    {
        const float* ip = idm_s + (eg * TS) * 12;
        f32x4 i0 = *(const f32x4*)ip, i1 = *(const f32x4*)(ip + 4), i2 = *(const f32x4*)(ip + 8);
        f32x2 s0 = *(const f32x2*)(sdv_acts + (eg * TS) * 2);
        ego_v = i0[0]; ego_x = i0[3];
        ENV_X9(i0, i1, i2, s0)
        PACK_ENV_HI(bh)
        const float* ip1 = idm_s + (eg * TS + 1) * 12;
        cur0 = *(const f32x4*)ip1; cur1 = *(const f32x4*)(ip1 + 4); cur2 = *(const f32x4*)(ip1 + 8);
        curs = *(const f32x2*)(sdv_acts + (eg * TS + 1) * 2);
    }
    __syncthreads();   // As ready -- LAST barrier; loop is barrier-free

    // ---------------- 40-step recurrence, wave-local, single bf16 stream ----------------
    // read swizzle: lane lb reads row 16*mt+lb -> row&15 == lb
    const int sw = lb << 4;
    const int k0 = (16 * lg) ^ sw;
    const int k1 = (64 + 16 * lg) ^ sw;
    const int k2 = (128 + 16 * lg) ^ sw;
    const int k3 = (192 + 16 * lg) ^ sw;
    const char* Abase = sm + lb * 256;

    for (int t = 0; t < TS; ++t) {
        bf16x8 nbh[4];
        float pact = 0.f;
        #pragma unroll
        for (int mt = 0; mt < NMT; ++mt) {
            float g0, g1, g2, g3;
            asm("v_accvgpr_read_b32 %0, %1" : "=v"(g0) : "a"(gka[4 * mt + 0]));
            asm("v_accvgpr_read_b32 %0, %1" : "=v"(g1) : "a"(gka[4 * mt + 1]));
            asm("v_accvgpr_read_b32 %0, %1" : "=v"(g2) : "a"(gka[4 * mt + 2]));
            asm("v_accvgpr_read_b32 %0, %1" : "=v"(g3) : "a"(gka[4 * mt + 3]));
            f32x4 ac = (f32x4){g0, g1, g2, g3};
            const char* ap = Abase + mt * 4096;
            bf16x8 a0 = *(const bf16x8*)(ap + k0);
            ac = __builtin_amdgcn_mfma_f32_16x16x32_bf16(a0, bh[0], ac, 0, 0, 0);
            bf16x8 a1 = *(const bf16x8*)(ap + k1);
            ac = __builtin_amdgcn_mfma_f32_16x16x32_bf16(a1, bh[1], ac, 0, 0, 0);
            bf16x8 a2 = *(const bf16x8*)(ap + k2);
            ac = __builtin_amdgcn_mfma_f32_16x16x32_bf16(a2, bh[2], ac, 0, 0, 0);
            bf16x8 a3 = *(const bf16x8*)(ap + k3);
            ac = __builtin_amdgcn_mfma_f32_16x16x32_bf16(a3, bh[3], ac, 0, 0, 0);
            // gates: ac = (i,f,g,o) for unit u = 4*mt+lg of batch lb
            const float cc = sigf(ac[1]) * c_st[mt] + sigf(ac[0]) * tanhf_(ac[2]);
            const float hh = sigf(ac[3]) * tanhf_(cc);
            c_st[mt] = cc;
            pact += hh * wd_reg[mt];
            const int kcq = mt & 3, jjq = mt >> 2;
            nbh[kcq][jjq] = (short)f2bf(hh);
        }
        pact += __shfl_xor(pact, 16);
        pact += __shfl_xor(pact, 32);
        const float act = pact + bd0;
        if (lg == 0) out[eg * TS + t] = act;

        if (t < TS - 1) {
            ego_v += act * 0.1f;
            ego_x += ego_v * 0.1f + 0.005f * act;
            ENV_X9(cur0, cur1, cur2, curs)
            PACK_ENV_HI(nbh)
            // never-written slots must be zero (mtk 25..27)
            nbh[1][6] = 0; nbh[2][6] = 0; nbh[3][6] = 0;
            #pragma unroll
            for (int kc = 0; kc < 4; ++kc) bh[kc] = nbh[kc];
            if (t < TS - 2) {
                const float* ip = idm_s + (eg * TS + t + 2) * 12;
                cur0 = *(const f32x4*)ip; cur1 = *(const f32x4*)(ip + 4); cur2 = *(const f32x4*)(ip + 8);
                curs = *(const f32x2*)(sdv_acts + (eg * TS + t + 2) * 2);
            }
        }
    }
}

extern "C" void kernel_launch(void* const* d_in, const int* in_sizes, int n_in,
                              void* d_out, int out_size, void* d_ws, size_t ws_size,
                              hipStream_t stream) {
    const float* sampled_z = (const float*)d_in[0];
    const float* idm_s     = (const float*)d_in[1];
    const float* sdv_acts  = (const float*)d_in[2];
    const float* W1        = (const float*)d_in[3];
    const float* b1        = (const float*)d_in[4];
    const float* W2        = (const float*)d_in[5];
    const float* b2        = (const float*)d_in[6];
    const float* Wk        = (const float*)d_in[7];
    const float* Wr        = (const float*)d_in[8];
    const float* bl        = (const float*)d_in[9];
    const float* Wd        = (const float*)d_in[10];
    const float* bd        = (const float*)d_in[11];
    const float* sc_mean   = (const float*)d_in[12];
    const float* sc_var    = (const float*)d_in[13];
    float* out = (float*)d_out;

    unsigned short* Am = (unsigned short*)d_ws;       // [400][128] bf16 sigma-layout
    unsigned short* Ah = Am + 400 * 128;              // Wk hi
    unsigned short* Al = Ah + 400 * 128;              // Wk lo

    hipLaunchKernelGGL(prep_kernel, dim3(200), dim3(256), 0, stream, Wr, Wk, Am, Ah, Al);
    hipLaunchKernelGGL(fwdsim_kernel, dim3(16384 / BT), dim3(NT), 0, stream,
                       sampled_z, idm_s, sdv_acts, W1, b1, W2, b2, bl, Wd, bd,
                       sc_mean, sc_var, Am, Ah, Al, out);
}